// Round 8
// baseline (241.520 us; speedup 1.0000x reference)
//
#include <hip/hip_runtime.h>

static constexpr int NROWS = 32768;
static constexpr int FIN   = 1024;
static constexpr int FOUT  = 512;
static constexpr int NREP  = 16;     // u accumulator groups (written by k2b)

// ws layout (~4.4 MB of the 512 MiB available):
//   double e[32768]        : unnormalized exp(scores)        (256 KB)
//   double hpart[1024]     : h[k] * (W@a1)[k]                (8 KB)
//   double zpart[1024]     : per-K2-block partial of Z       (8 KB)
//   float  v[1024]         : W @ a2                          (4 KB)
//   float  u16[16][1024]   : group-reduced u accumulators    (64 KB)
//   float  part[1024][1024]: per-block u partials            (4 MB)
//
// d_out layout: [0:512) out fp32 | [512:33280) attention2 as 0.0/1.0

// ---------------------------------------------------------------------------
// K1: one wave per k (1024 waves). No atomics, no zeroing (k2b overwrites u16).
// ---------------------------------------------------------------------------
__global__ __launch_bounds__(256) void k1_prep(const float* __restrict__ W,
                                               const float* __restrict__ a,
                                               const float* __restrict__ h,
                                               float* __restrict__ v,
                                               double* __restrict__ hpart) {
    const int k    = (blockIdx.x * blockDim.x + threadIdx.x) >> 6;  // 0..1023
    const int lane = threadIdx.x & 63;

    const float4* Wrow = (const float4*)(W + (size_t)k * FOUT);
    float4 w0 = Wrow[lane];
    float4 w1 = Wrow[64 + lane];

    const float4* a4 = (const float4*)a;
    float4 a1_0 = a4[lane];
    float4 a1_1 = a4[64 + lane];
    float4 a2_0 = a4[128 + lane];
    float4 a2_1 = a4[192 + lane];

    double d1 = (double)w0.x * a1_0.x + (double)w0.y * a1_0.y +
                (double)w0.z * a1_0.z + (double)w0.w * a1_0.w +
                (double)w1.x * a1_1.x + (double)w1.y * a1_1.y +
                (double)w1.z * a1_1.z + (double)w1.w * a1_1.w;
    double d2 = (double)w0.x * a2_0.x + (double)w0.y * a2_0.y +
                (double)w0.z * a2_0.z + (double)w0.w * a2_0.w +
                (double)w1.x * a2_1.x + (double)w1.y * a2_1.y +
                (double)w1.z * a2_1.z + (double)w1.w * a2_1.w;

    #pragma unroll
    for (int off = 32; off; off >>= 1) {
        d1 += __shfl_xor(d1, off);
        d2 += __shfl_xor(d2, off);
    }
    if (lane == 0) {
        v[k]     = (float)d2;
        hpart[k] = (double)h[k] * d1;
    }
}

// ---------------------------------------------------------------------------
// K2: 1024 blocks x 256 threads. Row-dbuf structure (round 7), UNCHANGED.
// ROUND 8 (measurement): whole body repeated nrep(=2) times.
//   - rep0 runs in the true post-fill state (L3 cold / fill-drain), rep1 in
//     the warm state -> separates environment-bound from structure-bound.
//   - k2 duration doubles past the 77us fills -> first CLEAN k2 PMC row.
//   - memory clobber per rep defeats cross-rep load CSE; zacc/uacc re-init
//     per rep; all stores idempotent -> outputs bit-identical to round 7.
// ---------------------------------------------------------------------------
__global__ __launch_bounds__(256) void k2_main(const float* __restrict__ adj,
                                               const float* __restrict__ v,
                                               const double* __restrict__ hpart,
                                               double* __restrict__ e,
                                               float* __restrict__ part,  // [1024][1024]
                                               double* __restrict__ zpart,
                                               const int nrep) {
    __shared__ float  uls[4][1024];
    __shared__ double zls[4];

    const int wave  = threadIdx.x >> 6;               // 0..3
    const int lane  = threadIdx.x & 63;
    const int gwave = blockIdx.x * 4 + wave;          // 0..4095

    const int row0 = gwave * 8;
    const float4* base = (const float4*)(adj + (size_t)row0 * FIN) + lane;

    for (int rep = 0; rep < nrep; ++rep) {
        asm volatile("" ::: "memory");   // force fresh loads each rep

        float4 A[4], B[4];   // one row each

        // preload row 0 -> A, row 1 -> B
        #pragma unroll
        for (int q = 0; q < 4; ++q) A[q] = base[q * 64];
        #pragma unroll
        for (int q = 0; q < 4; ++q) B[q] = base[256 + q * 64];

        // c0 = sum(hpart), identical order in every wave
        double c0 = 0.0;
        #pragma unroll
        for (int j = 0; j < 16; ++j) c0 += hpart[j * 64 + lane];
        #pragma unroll
        for (int off = 32; off; off >>= 1) c0 += __shfl_xor(c0, off);

        const float4* v4 = (const float4*)v;
        float4 vf[4];
        #pragma unroll
        for (int q = 0; q < 4; ++q) vf[q] = v4[q * 64 + lane];

        float  uacc[4][4] = {};
        double zacc = 0.0;   // wave-uniform

        auto do_row = [&](float4 (&buf)[4], const int r) {
            double dot = 0.0;
            #pragma unroll
            for (int q = 0; q < 4; ++q) {
                dot += (double)buf[q].x * vf[q].x + (double)buf[q].y * vf[q].y +
                       (double)buf[q].z * vf[q].z + (double)buf[q].w * vf[q].w;
            }
            #pragma unroll
            for (int off = 32; off; off >>= 1) dot += __shfl_xor(dot, off);

            double s = c0 + dot;
            if (s < 0.0) s *= 0.1;           // leaky_relu(0.1)
            const double ev = exp(s);        // wave-uniform
            zacc += ev;
            if (lane == 0) e[row0 + r] = ev;

            const float evf = (float)ev;
            #pragma unroll
            for (int q = 0; q < 4; ++q) {
                uacc[q][0] += evf * buf[q].x;
                uacc[q][1] += evf * buf[q].y;
                uacc[q][2] += evf * buf[q].z;
                uacc[q][3] += evf * buf[q].w;
            }

            if (r + 2 < 8) {
                #pragma unroll
                for (int q = 0; q < 4; ++q) buf[q] = base[(r + 2) * 256 + q * 64];
            }
        };

        do_row(A, 0); do_row(B, 1);
        do_row(A, 2); do_row(B, 3);
        do_row(A, 4); do_row(B, 5);
        do_row(A, 6); do_row(B, 7);

        // per-wave u partial -> LDS (conflict-free b128 writes)
        float4* uls4w = (float4*)&uls[wave][0];
        #pragma unroll
        for (int q = 0; q < 4; ++q)
            uls4w[q * 64 + lane] =
                make_float4(uacc[q][0], uacc[q][1], uacc[q][2], uacc[q][3]);

        if (lane == 0) zls[wave] = zacc;

        __syncthreads();

        // cross-wave reduce; thread t owns cols 4t..4t+3
        const int t = threadIdx.x;
        const float4* uls4 = (const float4*)uls;
        float4 s0 = uls4[t];
        float4 s1 = uls4[256 + t];
        float4 s2 = uls4[512 + t];
        float4 s3 = uls4[768 + t];

        float4* prow = (float4*)(part + (size_t)blockIdx.x * 1024);
        prow[t] = make_float4(s0.x + s1.x + s2.x + s3.x,
                              s0.y + s1.y + s2.y + s3.y,
                              s0.z + s1.z + s2.z + s3.z,
                              s0.w + s1.w + s2.w + s3.w);

        if (t == 0) zpart[blockIdx.x] = zls[0] + zls[1] + zls[2] + zls[3];

        __syncthreads();   // uls safe to rewrite next rep
    }
}

// ---------------------------------------------------------------------------
// K2b: reduce part[1024][1024] -> u16[16][1024]. 64 blocks x 256 threads.
// ---------------------------------------------------------------------------
__global__ __launch_bounds__(256) void k2b_reduce(const float* __restrict__ part,
                                                  float* __restrict__ u16) {
    const int g   = blockIdx.x >> 2;          // 0..15
    const int c   = blockIdx.x & 3;           // 0..3
    const int col = c * 256 + threadIdx.x;    // 0..1023
    const float* p = part + (size_t)g * 64 * 1024 + col;
    float acc = 0.f;
    #pragma unroll 8
    for (int b = 0; b < 64; ++b) acc += p[(size_t)b * 1024];
    u16[g * 1024 + col] = acc;
}

// ---------------------------------------------------------------------------
// Deterministic Z from zpart (identical order in every block).
// ---------------------------------------------------------------------------
__device__ __forceinline__ double block_reduce_Z(const double* __restrict__ zpart,
                                                 double* zs) {
    const int t = threadIdx.x;
    zs[t] = zpart[t] + zpart[256 + t] + zpart[512 + t] + zpart[768 + t];
    __syncthreads();
    for (int st = 128; st > 0; st >>= 1) {
        if (t < st) zs[t] += zs[t + st];
        __syncthreads();
    }
    double Z = zs[0];
    __syncthreads();
    return Z;
}

// ---------------------------------------------------------------------------
// K3 (fused): blocks 0..15  -> out[0:512] = (u/Z) @ W1
//             blocks 16..31 -> out[512+i] = (N*e_i > Z) ? 1 : 0
// ---------------------------------------------------------------------------
__global__ __launch_bounds__(256) void k3_final(const double* __restrict__ e,
                                                const double* __restrict__ zpart,
                                                const float* __restrict__ u16,
                                                const float* __restrict__ W1,
                                                float* __restrict__ out) {
    __shared__ double zs[256];
    const double Z = block_reduce_Z(zpart, zs);
    const int t = threadIdx.x;

    if (blockIdx.x < 16) {
        __shared__ float us[1024];
        __shared__ float red[8][32];

        #pragma unroll
        for (int g = 0; g < 4; ++g) {
            const int k = g * 256 + t;
            float s = 0.f;
            #pragma unroll
            for (int rep = 0; rep < NREP; ++rep) s += u16[rep * 1024 + k];
            us[k] = s;
        }
        __syncthreads();

        const int cl  = t & 31;
        const int kg  = t >> 5;
        const int col = blockIdx.x * 32 + cl;
        float acc = 0.f;
        #pragma unroll 8
        for (int kk = 0; kk < 128; ++kk) {
            const int k = kg * 128 + kk;
            acc += us[k] * W1[(size_t)k * FOUT + col];
        }
        red[kg][cl] = acc;
        __syncthreads();
        if (t < 32) {
            float tot = 0.f;
            #pragma unroll
            for (int g = 0; g < 8; ++g) tot += red[g][t];
            out[blockIdx.x * 32 + t] = (float)((double)tot / Z);
        }
    } else {
        const int i0 = (blockIdx.x - 16) * 2048 + t * 8;
        const double2* e2 = (const double2*)(e + i0);
        const double thr = Z;
        float r[8];
        #pragma unroll
        for (int q = 0; q < 4; ++q) {
            double2 ev = e2[q];
            r[2 * q]     = (ev.x * (double)NROWS > thr) ? 1.0f : 0.0f;
            r[2 * q + 1] = (ev.y * (double)NROWS > thr) ? 1.0f : 0.0f;
        }
        float4* o4 = (float4*)(out + FOUT + i0);
        o4[0] = make_float4(r[0], r[1], r[2], r[3]);
        o4[1] = make_float4(r[4], r[5], r[6], r[7]);
    }
}

extern "C" void kernel_launch(void* const* d_in, const int* in_sizes, int n_in,
                              void* d_out, int out_size, void* d_ws, size_t ws_size,
                              hipStream_t stream) {
    const float* h   = (const float*)d_in[0];   // (1, 1024)
    const float* adj = (const float*)d_in[1];   // (32768, 1024)
    const float* W   = (const float*)d_in[2];   // (1024, 512)
    const float* a   = (const float*)d_in[3];   // (1024, 1)
    const float* W1  = (const float*)d_in[4];   // (1024, 512)
    float* out = (float*)d_out;

    double* e     = (double*)d_ws;              // [32768]
    double* hpart = e + NROWS;                  // [1024]
    double* zpart = hpart + 1024;               // [1024]
    float*  v     = (float*)(zpart + 1024);     // [1024]
    float*  u16   = v + 1024;                   // [16][1024]
    float*  part  = u16 + 16 * 1024;            // [1024][1024]

    k1_prep<<<dim3(256),  dim3(256), 0, stream>>>(W, a, h, v, hpart);
    k2_main<<<dim3(1024), dim3(256), 0, stream>>>(adj, v, hpart, e, part, zpart, 2);
    k2b_reduce<<<dim3(64), dim3(256), 0, stream>>>(part, u16);
    k3_final<<<dim3(32),  dim3(256), 0, stream>>>(e, zpart, u16, W1, out);
}

// Round 9
// 221.863 us; speedup vs baseline: 1.0886x; 1.0886x over previous
//
#include <hip/hip_runtime.h>

static constexpr int NROWS = 32768;
static constexpr int FIN   = 1024;
static constexpr int FOUT  = 512;
static constexpr int NREP  = 16;     // u accumulator groups (written by k2b)

// ws layout (~4.4 MB of the 512 MiB available):
//   double e[32768]        : unnormalized exp(scores)        (256 KB)
//   double hpart[1024]     : h[k] * (W@a1)[k]                (8 KB)
//   double zpart[1024]     : per-K2-block partial of Z       (8 KB)
//   float  v[1024]         : W @ a2                          (4 KB)
//   float  u16[16][1024]   : group-reduced u accumulators    (64 KB)
//   float  part[1024][1024]: per-block u partials            (4 MB)
//
// d_out layout: [0:512) out fp32 | [512:33280) attention2 as 0.0/1.0

// ---------------------------------------------------------------------------
// K1: one wave per k (1024 waves). No atomics, no zeroing (k2b overwrites u16).
// ---------------------------------------------------------------------------
__global__ __launch_bounds__(256) void k1_prep(const float* __restrict__ W,
                                               const float* __restrict__ a,
                                               const float* __restrict__ h,
                                               float* __restrict__ v,
                                               double* __restrict__ hpart) {
    const int k    = (blockIdx.x * blockDim.x + threadIdx.x) >> 6;  // 0..1023
    const int lane = threadIdx.x & 63;

    const float4* Wrow = (const float4*)(W + (size_t)k * FOUT);
    float4 w0 = Wrow[lane];
    float4 w1 = Wrow[64 + lane];

    const float4* a4 = (const float4*)a;
    float4 a1_0 = a4[lane];
    float4 a1_1 = a4[64 + lane];
    float4 a2_0 = a4[128 + lane];
    float4 a2_1 = a4[192 + lane];

    double d1 = (double)w0.x * a1_0.x + (double)w0.y * a1_0.y +
                (double)w0.z * a1_0.z + (double)w0.w * a1_0.w +
                (double)w1.x * a1_1.x + (double)w1.y * a1_1.y +
                (double)w1.z * a1_1.z + (double)w1.w * a1_1.w;
    double d2 = (double)w0.x * a2_0.x + (double)w0.y * a2_0.y +
                (double)w0.z * a2_0.z + (double)w0.w * a2_0.w +
                (double)w1.x * a2_1.x + (double)w1.y * a2_1.y +
                (double)w1.z * a2_1.z + (double)w1.w * a2_1.w;

    #pragma unroll
    for (int off = 32; off; off >>= 1) {
        d1 += __shfl_xor(d1, off);
        d2 += __shfl_xor(d2, off);
    }
    if (lane == 0) {
        v[k]     = (float)d2;
        hpart[k] = (double)h[k] * d1;
    }
}

// ---------------------------------------------------------------------------
// K2: 1024 blocks x 256 threads (32 rows/block, 8 rows/wave). Single adj pass.
// ROUND 9: the per-row 6-step f64 shfl butterflies (R8 measured: warm
// structure = 24us, ~20us of it serial compute; butterflies dominate) are
// replaced by ONE block-level LDS tree reduce + ONE packed exp for all 32
// rows. Per-lane 16-elem f64 dot chains and all uacc/e-store orders are
// unchanged; only the cross-lane summation ORDER changes (<=1-ulp in e/Z,
// margins proven >> f32-eps by 9 passing rounds of f64-vs-f32-ref match).
// Rows stay in registers (R[32], R4/R5-proven) across the reduce barriers.
// ---------------------------------------------------------------------------
__global__ __launch_bounds__(256) void k2_main(const float* __restrict__ adj,
                                               const float* __restrict__ v,
                                               const double* __restrict__ hpart,
                                               double* __restrict__ e,
                                               float* __restrict__ part,  // [1024][1024]
                                               double* __restrict__ zpart) {
    __shared__ float  uls[4][1024];
    __shared__ double pd[32][65];     // per-lane dot partials (+pad)
    __shared__ double red8[32][9];    // 8-way tree stage (+pad)
    __shared__ float  evs[32];        // f32 ev broadcast for uacc

    const int t    = threadIdx.x;
    const int wave = t >> 6;                       // 0..3
    const int lane = t & 63;
    const int rowb = blockIdx.x * 32;              // block's first row
    const int row0 = rowb + wave * 8;              // wave's first row

    const float4* base = (const float4*)(adj + (size_t)row0 * FIN) + lane;

    // ---- all 32 loads upfront (8 rows x 4 quarters) ----
    float4 R[32];
    #pragma unroll
    for (int r = 0; r < 8; ++r)
        #pragma unroll
        for (int q = 0; q < 4; ++q)
            R[r * 4 + q] = base[r * 256 + q * 64];

    // c0 = sum(hpart), fixed order (computed while loads are in flight)
    double c0 = 0.0;
    #pragma unroll
    for (int j = 0; j < 16; ++j) c0 += hpart[j * 64 + lane];
    #pragma unroll
    for (int off = 32; off; off >>= 1) c0 += __shfl_xor(c0, off);

    const float4* v4 = (const float4*)v;
    float4 vf[4];
    #pragma unroll
    for (int q = 0; q < 4; ++q) vf[q] = v4[q * 64 + lane];

    // per-row per-lane partial dot (IDENTICAL 16-elem f64 chain) -> LDS
    #pragma unroll
    for (int r = 0; r < 8; ++r) {
        double dot = 0.0;
        #pragma unroll
        for (int q = 0; q < 4; ++q) {
            const float4 dd = R[r * 4 + q];
            dot += (double)dd.x * vf[q].x + (double)dd.y * vf[q].y +
                   (double)dd.z * vf[q].z + (double)dd.w * vf[q].w;
        }
        pd[wave * 8 + r][lane] = dot;
    }
    __syncthreads();

    // phase A: 8-way tree, 256 threads: row j = t>>3, octet o = t&7
    {
        const int j = t >> 3;
        const int o = t & 7;
        double s8 = 0.0;
        #pragma unroll
        for (int i = 0; i < 8; ++i) s8 += pd[j][o * 8 + i];
        red8[j][o] = s8;
    }
    __syncthreads();

    // phase B: wave 0, lanes 0..31 — final sum, leaky, ONE exp for 32 rows
    if (t < 32) {
        double dot = 0.0;
        #pragma unroll
        for (int o = 0; o < 8; ++o) dot += red8[t][o];
        double s = c0 + dot;
        if (s < 0.0) s *= 0.1;             // leaky_relu(0.1)
        const double ev = exp(s);          // 32 rows in one packed call
        e[rowb + t] = ev;                  // coalesced 32 x 8B
        evs[t] = (float)ev;
        // block Z partial: fixed-order 32-lane butterfly (deterministic)
        double z = ev;
        #pragma unroll
        for (int off = 16; off; off >>= 1) z += __shfl_xor(z, off);
        if (t == 0) zpart[blockIdx.x] = z;
    }
    __syncthreads();

    // uacc from registers: row order 0..7, per-q x,y,z,w (order unchanged)
    float uacc[4][4] = {};
    #pragma unroll
    for (int r = 0; r < 8; ++r) {
        const float evf = evs[wave * 8 + r];   // LDS same-address broadcast
        #pragma unroll
        for (int q = 0; q < 4; ++q) {
            const float4 dd = R[r * 4 + q];
            uacc[q][0] += evf * dd.x;
            uacc[q][1] += evf * dd.y;
            uacc[q][2] += evf * dd.z;
            uacc[q][3] += evf * dd.w;
        }
    }

    // per-wave u partial -> LDS (conflict-free b128 writes)
    float4* uls4w = (float4*)&uls[wave][0];
    #pragma unroll
    for (int q = 0; q < 4; ++q)
        uls4w[q * 64 + lane] = make_float4(uacc[q][0], uacc[q][1], uacc[q][2], uacc[q][3]);

    __syncthreads();

    // cross-wave reduce; thread t owns cols 4t..4t+3
    const float4* uls4 = (const float4*)uls;
    float4 s0 = uls4[t];
    float4 s1 = uls4[256 + t];
    float4 s2 = uls4[512 + t];
    float4 s3 = uls4[768 + t];

    // privatized block partial: one coalesced float4 store, NO atomics
    float4* prow = (float4*)(part + (size_t)blockIdx.x * 1024);
    prow[t] = make_float4(s0.x + s1.x + s2.x + s3.x,
                          s0.y + s1.y + s2.y + s3.y,
                          s0.z + s1.z + s2.z + s3.z,
                          s0.w + s1.w + s2.w + s3.w);
}

// ---------------------------------------------------------------------------
// K2b: reduce part[1024][1024] -> u16[16][1024]. 64 blocks x 256 threads.
// ---------------------------------------------------------------------------
__global__ __launch_bounds__(256) void k2b_reduce(const float* __restrict__ part,
                                                  float* __restrict__ u16) {
    const int g   = blockIdx.x >> 2;          // 0..15
    const int c   = blockIdx.x & 3;           // 0..3
    const int col = c * 256 + threadIdx.x;    // 0..1023
    const float* p = part + (size_t)g * 64 * 1024 + col;
    float acc = 0.f;
    #pragma unroll 8
    for (int b = 0; b < 64; ++b) acc += p[(size_t)b * 1024];
    u16[g * 1024 + col] = acc;
}

// ---------------------------------------------------------------------------
// Deterministic Z from zpart (identical order in every block).
// ---------------------------------------------------------------------------
__device__ __forceinline__ double block_reduce_Z(const double* __restrict__ zpart,
                                                 double* zs) {
    const int t = threadIdx.x;
    zs[t] = zpart[t] + zpart[256 + t] + zpart[512 + t] + zpart[768 + t];
    __syncthreads();
    for (int st = 128; st > 0; st >>= 1) {
        if (t < st) zs[t] += zs[t + st];
        __syncthreads();
    }
    double Z = zs[0];
    __syncthreads();
    return Z;
}

// ---------------------------------------------------------------------------
// K3 (fused): blocks 0..15  -> out[0:512] = (u/Z) @ W1
//             blocks 16..31 -> out[512+i] = (N*e_i > Z) ? 1 : 0
// ---------------------------------------------------------------------------
__global__ __launch_bounds__(256) void k3_final(const double* __restrict__ e,
                                                const double* __restrict__ zpart,
                                                const float* __restrict__ u16,
                                                const float* __restrict__ W1,
                                                float* __restrict__ out) {
    __shared__ double zs[256];
    const double Z = block_reduce_Z(zpart, zs);
    const int t = threadIdx.x;

    if (blockIdx.x < 16) {
        __shared__ float us[1024];
        __shared__ float red[8][32];

        #pragma unroll
        for (int g = 0; g < 4; ++g) {
            const int k = g * 256 + t;
            float s = 0.f;
            #pragma unroll
            for (int rep = 0; rep < NREP; ++rep) s += u16[rep * 1024 + k];
            us[k] = s;
        }
        __syncthreads();

        const int cl  = t & 31;
        const int kg  = t >> 5;
        const int col = blockIdx.x * 32 + cl;
        float acc = 0.f;
        #pragma unroll 8
        for (int kk = 0; kk < 128; ++kk) {
            const int k = kg * 128 + kk;
            acc += us[k] * W1[(size_t)k * FOUT + col];
        }
        red[kg][cl] = acc;
        __syncthreads();
        if (t < 32) {
            float tot = 0.f;
            #pragma unroll
            for (int g = 0; g < 8; ++g) tot += red[g][t];
            out[blockIdx.x * 32 + t] = (float)((double)tot / Z);
        }
    } else {
        const int i0 = (blockIdx.x - 16) * 2048 + t * 8;
        const double2* e2 = (const double2*)(e + i0);
        const double thr = Z;
        float r[8];
        #pragma unroll
        for (int q = 0; q < 4; ++q) {
            double2 ev = e2[q];
            r[2 * q]     = (ev.x * (double)NROWS > thr) ? 1.0f : 0.0f;
            r[2 * q + 1] = (ev.y * (double)NROWS > thr) ? 1.0f : 0.0f;
        }
        float4* o4 = (float4*)(out + FOUT + i0);
        o4[0] = make_float4(r[0], r[1], r[2], r[3]);
        o4[1] = make_float4(r[4], r[5], r[6], r[7]);
    }
}

extern "C" void kernel_launch(void* const* d_in, const int* in_sizes, int n_in,
                              void* d_out, int out_size, void* d_ws, size_t ws_size,
                              hipStream_t stream) {
    const float* h   = (const float*)d_in[0];   // (1, 1024)
    const float* adj = (const float*)d_in[1];   // (32768, 1024)
    const float* W   = (const float*)d_in[2];   // (1024, 512)
    const float* a   = (const float*)d_in[3];   // (1024, 1)
    const float* W1  = (const float*)d_in[4];   // (1024, 512)
    float* out = (float*)d_out;

    double* e     = (double*)d_ws;              // [32768]
    double* hpart = e + NROWS;                  // [1024]
    double* zpart = hpart + 1024;               // [1024]
    float*  v     = (float*)(zpart + 1024);     // [1024]
    float*  u16   = v + 1024;                   // [16][1024]
    float*  part  = u16 + 16 * 1024;            // [1024][1024]

    k1_prep<<<dim3(256),  dim3(256), 0, stream>>>(W, a, h, v, hpart);
    k2_main<<<dim3(1024), dim3(256), 0, stream>>>(adj, v, hpart, e, part, zpart);
    k2b_reduce<<<dim3(64), dim3(256), 0, stream>>>(part, u16);
    k3_final<<<dim3(32),  dim3(256), 0, stream>>>(e, zpart, u16, W1, out);
}